// Round 1
// 1647.726 us; speedup vs baseline: 1.6799x; 1.6799x over previous
//
#include <hip/hip_runtime.h>
#include <hip/hip_bf16.h>

#define IGNORE_INDEX (-100)
#define BETA 0.1f

typedef __bf16 bf16x8 __attribute__((ext_vector_type(8)));
typedef float  f32x4  __attribute__((ext_vector_type(4)));

__device__ __forceinline__ void gload_lds16(const void* g, void* l) {
  __builtin_amdgcn_global_load_lds((const __attribute__((address_space(1))) void*)g,
                                   (__attribute__((address_space(3))) void*)l, 16, 0, 0);
}

__device__ __forceinline__ unsigned short f2bf(float f) {
  __hip_bfloat16 h = __float2bfloat16(f);
  return __builtin_bit_cast(unsigned short, h);
}

#define PH_BARRIER()  __builtin_amdgcn_s_barrier()
#define LGKM0()       asm volatile("s_waitcnt lgkmcnt(0)" ::: "memory")
#define VMCNT(N)      asm volatile("s_waitcnt vmcnt(" #N ")" ::: "memory")
#define SCHED_FENCE() __builtin_amdgcn_sched_barrier(0)

// ---------------- cast fp32 -> bf16, 8 elems/thread ----------------
__global__ void cast_f32_bf16_k(const float* __restrict__ src,
                                unsigned short* __restrict__ dst, long long n) {
  long long i = (long long)blockIdx.x * blockDim.x + threadIdx.x;
  long long b = i * 8;
  if (b + 8 > n) return;
  const float4* s4 = (const float4*)(src + b);
  float4 a = s4[0], c = s4[1];
  uint4 o;
  o.x = (unsigned)f2bf(a.x) | ((unsigned)f2bf(a.y) << 16);
  o.y = (unsigned)f2bf(a.z) | ((unsigned)f2bf(a.w) << 16);
  o.z = (unsigned)f2bf(c.x) | ((unsigned)f2bf(c.y) << 16);
  o.w = (unsigned)f2bf(c.z) | ((unsigned)f2bf(c.w) << 16);
  *(uint4*)(dst + b) = o;
}

// ---------------- 256x256 8-phase GEMM + per-vtile LSE partials ----------------
// A: bf16 [4096][2048], B: bf16 [32000][2048] (NT). BK=64, 8 waves (2Mx4N).
// LDS: 2 bufs x (A 32KB + B 32KB) = 128 KiB. Swizzle: 16B-chunk ^= (row&7),
// applied on the *global source* of global_load_lds (dest stays linear) and on
// the ds_read address (rule #21: both-sides-or-neither).
// partials: [4096][125] float2 {max, sumexp}; label_logit: [4096].

template<int MB>
__device__ __forceinline__ void ld_a(bf16x8 (&af)[4][2], const char* base,
                                     int aoff0, int aoff1) {
#pragma unroll
  for (int m = 0; m < 4; m++) {
    af[m][0] = *(const bf16x8*)(base + aoff0 + (MB + m) * 2048);
    af[m][1] = *(const bf16x8*)(base + aoff1 + (MB + m) * 2048);
  }
}

__device__ __forceinline__ void ld_b(bf16x8 (&bfr)[4][2], const char* base,
                                     int boff0, int boff1) {
#pragma unroll
  for (int n = 0; n < 4; n++) {
    bfr[n][0] = *(const bf16x8*)(base + boff0 + n * 2048);
    bfr[n][1] = *(const bf16x8*)(base + boff1 + n * 2048);
  }
}

template<int MB, int NH>
__device__ __forceinline__ void mfma_quad(f32x4 (&acc)[8][4], bf16x8 (&af)[4][2],
                                          bf16x8 (&bfr)[4][2]) {
#pragma unroll
  for (int m = 0; m < 4; m++)
#pragma unroll
    for (int n = 0; n < 2; n++)
#pragma unroll
      for (int k = 0; k < 2; k++)
        acc[MB + m][NH * 2 + n] = __builtin_amdgcn_mfma_f32_16x16x32_bf16(
            af[m][k], bfr[NH * 2 + n][k], acc[MB + m][NH * 2 + n], 0, 0, 0);
}

// stage one 128x64 half-tile: 512 threads x 2 x 16B
__device__ __forceinline__ void stage2(const unsigned short* s, char* d) {
  gload_lds16(s, d);
  gload_lds16(s + 16384, d + 1024);   // +8 rows (8*2048 elems), next 1KB region
}

__global__ __launch_bounds__(512, 2) void gemm_lse(
    const unsigned short* __restrict__ A,
    const unsigned short* __restrict__ B,
    const int* __restrict__ labels,
    float2* __restrict__ partials,
    float* __restrict__ label_logit) {
  // XCD-aware swizzle: 2000 blocks, 2000%8==0 -> bijective simple form.
  int bid = blockIdx.x;
  int swz = (bid & 7) * 250 + (bid >> 3);
  const int m0 = (swz & 15) * 256;      // 16 mtiles (fast: A panels cycle in L2)
  const int vtile = swz >> 4;           // 0..124
  const int n0 = vtile * 256;

  const int tid = threadIdx.x;
  const int lane = tid & 63;
  const int w = tid >> 6;
  const int wm = w >> 2, wn = w & 3;    // 2x4 wave grid; wave output 128x64
  const int quad = lane >> 4, r16 = lane & 15;

  __shared__ char smem[131072] __attribute__((aligned(128)));
  char* smemc = smem;
  char* buf0 = smemc;                   // A @ +0 (32KB), B @ +32768 (32KB)
  char* buf1 = smemc + 65536;

  // ---- staging addresses ----
  // thread covers rows (w*2+j)*8 + (lane>>3), 16B chunk pos lane&7, per half-tile.
  // inverse swizzle on source: chunk_src = (lane&7) ^ (row&7) = (lane&7)^(lane>>3)
  const int csw = ((lane & 7) ^ (lane >> 3)) * 8;
  const unsigned short* Ag = A + (size_t)(m0 + w * 16 + (lane >> 3)) * 2048 + csw;
  const unsigned short* Bg = B + (size_t)(n0 + w * 16 + (lane >> 3)) * 2048 + csw;
  char* dstA = smemc + w * 2048 + lane * 16;   // linear LDS dest (gload_lds req.)
  char* dstB = dstA + 32768;

  // ---- ds_read addresses (swizzled): chunk_pos = (ks*4|quad) ^ (row&7) ----
  const int s7 = r16 & 7;
  const int c0 = ((quad ^ s7) << 4);
  const int c1 = (((4 | quad) ^ s7) << 4);
  const int aoff0 = wm * 16384 + r16 * 128 + c0;
  const int aoff1 = wm * 16384 + r16 * 128 + c1;
  const int brow = (wn & 1) * 64 + r16;
  const int boff0 = 32768 + (wn >> 1) * 16384 + brow * 128 + c0;
  const int boff1 = 32768 + (wn >> 1) * 16384 + brow * 128 + c1;

  bf16x8 af[4][2], bfr[4][2];
  f32x4 acc[8][4] = {};

  // ---- prologue: buf0 <- kt0 (4 halves), buf1 <- kt1 (B-lo,B-hi,A-lo) ----
  stage2(Bg,                dstB);
  stage2(Bg + 262144,       dstB + 16384);
  stage2(Ag,                dstA);
  stage2(Ag + 262144,       dstA + 16384);
  stage2(Bg + 64,           dstB + 65536);
  stage2(Bg + 262144 + 64,  dstB + 65536 + 16384);
  stage2(Ag + 64,           dstA + 65536);
  VMCNT(6);                 // drain buf0's 8 loads; buf1's 6 stay in flight
  PH_BARRIER();

#pragma unroll 1
  for (int i = 0; i < 16; ++i) {
    const int kt1 = 2 * i + 1, kt2 = 2 * i + 2, kt3 = 2 * i + 3;
    const bool full = (i < 15);

    // ===== K-tile 2i (buf0): phases 1-4 =====
    // P1: read A[m0..3]+B[all]; stage buf1.A-hi <- kt1
    ld_a<0>(af, buf0, aoff0, aoff1);
    ld_b(bfr, buf0, boff0, boff1);
    stage2(Ag + 262144 + (size_t)kt1 * 64, dstA + 65536 + 16384);
    SCHED_FENCE(); PH_BARRIER(); LGKM0();
    __builtin_amdgcn_s_setprio(1); mfma_quad<0, 0>(acc, af, bfr);
    __builtin_amdgcn_s_setprio(0); SCHED_FENCE(); PH_BARRIER();
    // P2: stage buf0.B-lo <- kt2 (B last read in P1 -> safe)
    if (full) stage2(Bg + (size_t)kt2 * 64, dstB);
    SCHED_FENCE(); PH_BARRIER();
    __builtin_amdgcn_s_setprio(1); mfma_quad<0, 1>(acc, af, bfr);
    __builtin_amdgcn_s_setprio(0); SCHED_FENCE(); PH_BARRIER();
    // P3: read A[m4..7]; stage buf0.B-hi <- kt2
    ld_a<4>(af, buf0, aoff0, aoff1);
    if (full) stage2(Bg + 262144 + (size_t)kt2 * 64, dstB + 16384);
    SCHED_FENCE(); PH_BARRIER(); LGKM0();
    __builtin_amdgcn_s_setprio(1); mfma_quad<4, 0>(acc, af, bfr);
    __builtin_amdgcn_s_setprio(0); SCHED_FENCE(); PH_BARRIER();
    // P4: stage buf0.A-lo <- kt2 (A last read in P3); counted vmcnt -> buf1 ready
    if (full) { stage2(Ag + (size_t)kt2 * 64, dstA); VMCNT(6); }
    else      { VMCNT(0); }
    SCHED_FENCE(); PH_BARRIER();
    __builtin_amdgcn_s_setprio(1); mfma_quad<4, 1>(acc, af, bfr);
    __builtin_amdgcn_s_setprio(0); SCHED_FENCE(); PH_BARRIER();

    // ===== K-tile 2i+1 (buf1): phases 5-8 =====
    // P5: read A[m0..3]+B[all] from buf1; stage buf0.A-hi <- kt2
    ld_a<0>(af, buf1, aoff0, aoff1);
    ld_b(bfr, buf1, boff0, boff1);
    if (full) stage2(Ag + 262144 + (size_t)kt2 * 64, dstA + 16384);
    SCHED_FENCE(); PH_BARRIER(); LGKM0();
    __builtin_amdgcn_s_setprio(1); mfma_quad<0, 0>(acc, af, bfr);
    __builtin_amdgcn_s_setprio(0); SCHED_FENCE(); PH_BARRIER();
    // P6: stage buf1.B-lo <- kt3
    if (full) stage2(Bg + (size_t)kt3 * 64, dstB + 65536);
    SCHED_FENCE(); PH_BARRIER();
    __builtin_amdgcn_s_setprio(1); mfma_quad<0, 1>(acc, af, bfr);
    __builtin_amdgcn_s_setprio(0); SCHED_FENCE(); PH_BARRIER();
    // P7: read A[m4..7]; stage buf1.B-hi <- kt3
    ld_a<4>(af, buf1, aoff0, aoff1);
    if (full) stage2(Bg + 262144 + (size_t)kt3 * 64, dstB + 65536 + 16384);
    SCHED_FENCE(); PH_BARRIER(); LGKM0();
    __builtin_amdgcn_s_setprio(1); mfma_quad<4, 0>(acc, af, bfr);
    __builtin_amdgcn_s_setprio(0); SCHED_FENCE(); PH_BARRIER();
    // P8: stage buf1.A-lo <- kt3; counted vmcnt -> buf0(kt2) ready for next P1
    if (full) { stage2(Ag + (size_t)kt3 * 64, dstA + 65536); VMCNT(6); }
    SCHED_FENCE(); PH_BARRIER();
    __builtin_amdgcn_s_setprio(1); mfma_quad<4, 1>(acc, af, bfr);
    __builtin_amdgcn_s_setprio(0); SCHED_FENCE(); PH_BARRIER();
  }

  // ---- epilogue: per-row max/sumexp over 256 cols + label pick ----
  __syncthreads();                      // full drain; tile LDS now dead -> overlay
  float2* red = (float2*)smemc;         // [4][256] per-wn partials (8KB)
  int* lbl = (int*)(smemc + 8192);      // [256] labels (1KB)
  if (tid < 256) lbl[tid] = labels[m0 + tid];

#pragma unroll
  for (int mi = 0; mi < 8; mi++) {
#pragma unroll
    for (int e = 0; e < 4; e++) {
      // C/D layout (verified): m-row = quad*4+e, n-col = r16
      float v0 = acc[mi][0][e], v1 = acc[mi][1][e], v2 = acc[mi][2][e], v3 = acc[mi][3][e];
      float mx = fmaxf(fmaxf(v0, v1), fmaxf(v2, v3));
#pragma unroll
      for (int d = 1; d < 16; d <<= 1) mx = fmaxf(mx, __shfl_xor(mx, d));
      float s = expf(v0 - mx) + expf(v1 - mx) + expf(v2 - mx) + expf(v3 - mx);
#pragma unroll
      for (int d = 1; d < 16; d <<= 1) s += __shfl_xor(s, d);
      if (r16 == 0) {
        int row = wm * 128 + mi * 16 + quad * 4 + e;
        red[wn * 256 + row] = make_float2(mx, s);
      }
    }
  }
  __syncthreads();

#pragma unroll
  for (int mi = 0; mi < 8; mi++) {
#pragma unroll
    for (int e = 0; e < 4; e++) {
      int row = wm * 128 + mi * 16 + quad * 4 + e;
      int lb = lbl[row];
#pragma unroll
      for (int ni = 0; ni < 4; ni++) {
        int col = n0 + wn * 64 + ni * 16 + r16;
        if (lb == col) label_logit[m0 + row] = acc[mi][ni][e];
      }
    }
  }
  if (tid < 256) {
    float2 p0 = red[tid], p1 = red[256 + tid], p2 = red[512 + tid], p3 = red[768 + tid];
    float M = fmaxf(fmaxf(p0.x, p1.x), fmaxf(p2.x, p3.x));
    float S = p0.y * expf(p0.x - M) + p1.y * expf(p1.x - M) +
              p2.y * expf(p2.x - M) + p3.y * expf(p3.x - M);
    partials[(size_t)(m0 + tid) * 125 + vtile] = make_float2(M, S);
  }
}

// ---------------- one wave per row: combine 125 partials -> row logp ----------------
__global__ void row_lp_k(const float2* __restrict__ parts,   // [2][4096][125]
                         const float* __restrict__ lablog,   // [2][4096]
                         float* __restrict__ rowlp) {        // [2][4096]
  int row = blockIdx.x * 4 + (threadIdx.x >> 6);             // 0..8191
  int lane = threadIdx.x & 63;
  const float2* P = parts + (size_t)row * 125;
  float m = -1e30f, s = 0.f;
  for (int j = lane; j < 125; j += 64) {
    float2 p = P[j];
    if (p.x > m) { s = s * expf(m - p.x) + p.y; m = p.x; }
    else          s += p.y * expf(p.x - m);
  }
#pragma unroll
  for (int d = 1; d < 64; d <<= 1) {
    float om = __shfl_xor(m, d);
    float os = __shfl_xor(s, d);
    float M = fmaxf(m, om);
    s = s * expf(m - M) + os * expf(om - M);
    m = M;
  }
  if (lane == 0) rowlp[row] = lablog[row] - (m + logf(s));
}

// ---------------- per-batch masked mean ----------------
__global__ void reduce_batch_k(const float* __restrict__ rowlp,
                               const int* __restrict__ labels,
                               float* __restrict__ blp) {     // [2][8]
  int path = blockIdx.x >> 3, batch = blockIdx.x & 7;
  int t = threadIdx.x;                                        // 0..511
  int lab = labels[batch * 512 + t];
  float v = rowlp[path * 4096 + batch * 512 + t];
  bool ok = (lab != IGNORE_INDEX);
  float sum = ok ? v : 0.f;
  float cnt = ok ? 1.f : 0.f;
#pragma unroll
  for (int d = 1; d < 64; d <<= 1) { sum += __shfl_xor(sum, d); cnt += __shfl_xor(cnt, d); }
  __shared__ float ws_[8], wc_[8];
  if ((t & 63) == 0) { ws_[t >> 6] = sum; wc_[t >> 6] = cnt; }
  __syncthreads();
  if (t == 0) {
    float S = 0.f, C = 0.f;
    for (int k = 0; k < 8; k++) { S += ws_[k]; C += wc_[k]; }
    blp[blockIdx.x] = (C > 0.f) ? S / C : 0.f;
  }
}

// ---------------- final KTO loss ----------------
__global__ void final_loss(const float* __restrict__ batch_lp, float* __restrict__ out) {
  if (threadIdx.x == 0 && blockIdx.x == 0) {
    float tot = 0.f;
    for (int b = 0; b < 8; b++) {
      float d = batch_lp[b] - batch_lp[8 + b];   // policy - ref
      float z = (b < 4) ? (BETA * d) : (-BETA * d);
      float sg = 1.f / (1.f + expf(-z));
      tot += 1.f - sg;
    }
    out[0] = tot / 8.f;
  }
}

extern "C" void kernel_launch(void* const* d_in, const int* in_sizes, int n_in,
                              void* d_out, int out_size, void* d_ws, size_t ws_size,
                              hipStream_t stream) {
  const float* x     = (const float*)d_in[0];
  const float* ref_x = (const float*)d_in[1];
  const int*   y     = (const int*)d_in[2];
  const float* W     = (const float*)d_in[3];
  const float* ref_W = (const float*)d_in[4];

  // workspace (~173 MB): xb, rxb, Wb (reused per path), partials [2][4096][125],
  // label_logit [2][4096], rowlp [2][4096], batch_lp [2][8]
  unsigned short* xb  = (unsigned short*)d_ws;
  unsigned short* rxb = xb + (size_t)8388608;
  unsigned short* Wb  = rxb + (size_t)8388608;
  char* p2 = (char*)(Wb + (size_t)65536000);
  float2* parts = (float2*)p2;                                   // 8,192,000 B
  float* lablog = (float*)(p2 + (size_t)8192000);                // 32768 B
  float* rowlp  = lablog + 8192;                                 // 32768 B
  float* blp    = rowlp + 8192;                                  // 64 B

  cast_f32_bf16_k<<<4096, 256, 0, stream>>>(x, xb, 8388608LL);
  cast_f32_bf16_k<<<4096, 256, 0, stream>>>(ref_x, rxb, 8388608LL);

  // path 0: policy
  cast_f32_bf16_k<<<32000, 256, 0, stream>>>(W, Wb, 65536000LL);
  gemm_lse<<<2000, 512, 0, stream>>>(xb, Wb, y, parts, lablog);

  // path 1: reference (reuse Wb; stream order serializes)
  cast_f32_bf16_k<<<32000, 256, 0, stream>>>(ref_W, Wb, 65536000LL);
  gemm_lse<<<2000, 512, 0, stream>>>(rxb, Wb, y, parts + (size_t)4096 * 125, lablog + 4096);

  row_lp_k<<<2048, 256, 0, stream>>>(parts, lablog, rowlp);
  reduce_batch_k<<<16, 512, 0, stream>>>(rowlp, y, blp);
  final_loss<<<1, 64, 0, stream>>>(blp, (float*)d_out);
}